// Round 9
// baseline (126.680 us; speedup 1.0000x reference)
//
#include <hip/hip_runtime.h>

typedef float v2f __attribute__((ext_vector_type(2)));

#define HH 512
#define WW 512
#define NPLANES 96
#define BLOCK 256         // 4 independent waves per block; no barriers anywhere
#define WPB 4             // waves per block
#define COLS_PB 64        // 1 column per lane
#define ROWS_PW 64        // rows per wave-tile
#define COL_TILES 8       // 512 / 64
#define ROW_GROUPS 2      // 8 row-bands / 4 waves
#define HALO 5
#define NS 11             // LDS ring slots == named register ring depth
#define SLOT_V2 96        // v2f pairs per slot (192 floats; data pairs 0..79, junk 80..95)
#define SLOT_FLOATS (SLOT_V2 * 2)
#define RING_FLOATS (NS * SLOT_FLOATS)   // per-wave ring: 8.25 KB
#define PADL 8            // pair p <-> global col C0-8+p

#define C1V 1e-4f
#define C2V 9e-4f
#define EPSV 1e-8f
#define NPIX 25165824.0f  // 32*3*512*512
#define NPART 6144        // 96 planes x 8 bands x 8 col-tiles

#define FMA2(a,b,c) __builtin_elementwise_fma((a),(b),(c))

__device__ __forceinline__ void gld4(const float* g, float* l) {
  __builtin_amdgcn_global_load_lds((const __attribute__((address_space(1))) void*)g,
                                   (__attribute__((address_space(3))) void*)l, 4, 0, 0);
}

// stage one interleaved {x,y} row into this wave's slot: 3 DMA instrs (4B/lane);
// rows outside [0,512) read the zero page (stride-0 also folds invalid cols).
__device__ __forceinline__ void dma_rowpair(float* dst, int rw,
    const float* pS0, unsigned st0, const float* pS1, unsigned st1,
    const float* pS2, unsigned st2, const float* zp)
{
  const bool rok = (unsigned)rw < (unsigned)HH;
  const float* a0 = rok ? (const float*)((uintptr_t)pS0 + (unsigned)rw * st0) : zp;
  const float* a1 = rok ? (const float*)((uintptr_t)pS1 + (unsigned)rw * st1) : zp;
  const float* a2 = rok ? (const float*)((uintptr_t)pS2 + (unsigned)rw * st2) : zp;
  gld4(a0, dst);
  gld4(a1, dst + 64);
  gld4(a2, dst + 128);
}

// ---- named variables only (no arrays -> nothing can fall to scratch) ----

// tap k of lane: one aligned ds_read_b64 gives {x,y} directly
#define TAP(K) { \
  const v2f tk = pb_[K]; \
  const v2f wt = wv##K * tk; \
  sa += wt; sb = FMA2(wt, tk, sb); sc = fmaf(wt.x, tk.y, sc); }

#define HBLUR(S) { \
  const v2f* pb_ = ldsv2w + (S) * SLOT_V2 + lane + 3; \
  v2f sa = {0.f, 0.f}, sb = {0.f, 0.f}; float sc = 0.f; \
  TAP(0) TAP(1) TAP(2) TAP(3) TAP(4) TAP(5) \
  TAP(6) TAP(7) TAP(8) TAP(9) TAP(10) \
  a##S = sa; b##S = sb; c##S = sc; }

// vertical 11-tap blur over named ring slots + SSIM epilogue
#define VEPI(p0,p1,p2,p3,p4,p5,p6,p7,p8,p9,p10) { \
  v2f ma = wv0 * a##p0; \
  ma = FMA2((v2f)(wv1),  a##p1,  ma); ma = FMA2((v2f)(wv2),  a##p2,  ma); \
  ma = FMA2((v2f)(wv3),  a##p3,  ma); ma = FMA2((v2f)(wv4),  a##p4,  ma); \
  ma = FMA2((v2f)(wv5),  a##p5,  ma); ma = FMA2((v2f)(wv6),  a##p6,  ma); \
  ma = FMA2((v2f)(wv7),  a##p7,  ma); ma = FMA2((v2f)(wv8),  a##p8,  ma); \
  ma = FMA2((v2f)(wv9),  a##p9,  ma); ma = FMA2((v2f)(wv10), a##p10, ma); \
  v2f mb = wv0 * b##p0; \
  mb = FMA2((v2f)(wv1),  b##p1,  mb); mb = FMA2((v2f)(wv2),  b##p2,  mb); \
  mb = FMA2((v2f)(wv3),  b##p3,  mb); mb = FMA2((v2f)(wv4),  b##p4,  mb); \
  mb = FMA2((v2f)(wv5),  b##p5,  mb); mb = FMA2((v2f)(wv6),  b##p6,  mb); \
  mb = FMA2((v2f)(wv7),  b##p7,  mb); mb = FMA2((v2f)(wv8),  b##p8,  mb); \
  mb = FMA2((v2f)(wv9),  b##p9,  mb); mb = FMA2((v2f)(wv10), b##p10, mb); \
  float mc = wv0 * c##p0; \
  mc = fmaf(wv1,  c##p1,  mc); mc = fmaf(wv2,  c##p2,  mc); \
  mc = fmaf(wv3,  c##p3,  mc); mc = fmaf(wv4,  c##p4,  mc); \
  mc = fmaf(wv5,  c##p5,  mc); mc = fmaf(wv6,  c##p6,  mc); \
  mc = fmaf(wv7,  c##p7,  mc); mc = fmaf(wv8,  c##p8,  mc); \
  mc = fmaf(wv9,  c##p9,  mc); mc = fmaf(wv10, c##p10, mc); \
  const v2f mm = ma * ma;                 /* {mx2, my2} */ \
  const float mxy = ma.x * ma.y; \
  const v2f sv = mb - mm;                 /* {sx2, sy2} */ \
  const float sxy = mc - mxy; \
  const float num = fmaf(2.f, mxy, C1V) * fmaf(2.f, sxy, C2V); \
  const float den = (mm.x + mm.y + C1V) * (sv.x + sv.y + C2V) + EPSV; \
  acc = fmaf(num, __builtin_amdgcn_rcpf(den), acc); }

// phase q: DMA row R0+8+q (3 instrs; 3 rows = 9 instrs in flight per wave) into
// retired slot (q+2)%11, counted vmcnt(9) -> row R0+5+q landed, h-blur it into
// ring slot (q+10)%11, vertical blur + epilogue for output row R0+q.
#define PHASE(QV, SNEW, SDMA, p0,p1,p2,p3,p4,p5,p6,p7,p8,p9,p10) { \
  dma_rowpair(wptr + (SDMA) * SLOT_FLOATS, R0 + 8 + (QV), \
              pS0, st0, pS1, st1, pS2, st2, zp); \
  asm volatile("s_waitcnt vmcnt(9)" ::: "memory"); \
  HBLUR(SNEW) \
  VEPI(p0,p1,p2,p3,p4,p5,p6,p7,p8,p9,p10) }

__global__ __launch_bounds__(BLOCK)
void ssim_main(const float* __restrict__ x, const float* __restrict__ y,
               float* __restrict__ ws)
{
  __shared__ float ldsF[WPB * RING_FLOATS];   // 33 KB: private ring per wave

  const int t = threadIdx.x;
  const int lane = t & 63;
  const int wid = t >> 6;
  const int colT = blockIdx.x;                 // 0..7
  const int wband = blockIdx.y * WPB + wid;    // 0..7 row band
  const int plane = blockIdx.z;                // 0..95
  const int C0 = colT * COLS_PB;
  const int R0 = wband * ROWS_PW;

  float* wptr = ldsF + wid * RING_FLOATS;
  const v2f* ldsv2w = (const v2f*)wptr;

  const float* xp = x + (ptrdiff_t)plane * (HH * WW);
  const float* yp = y + (ptrdiff_t)plane * (HH * WW);
  const float* zp = ws;                 // 256-float zero page (zeroed each launch)
  float* partial = ws + 256;

  // Gaussian window (exact reference formula), named scalars -> SGPRs
  float wv0, wv1, wv2, wv3, wv4, wv5, wv6, wv7, wv8, wv9, wv10;
#define WINIT(k) wv##k = expf(-((float)((k - 5) * (k - 5))) / 4.5f);
  WINIT(0) WINIT(1) WINIT(2) WINIT(3) WINIT(4) WINIT(5)
  WINIT(6) WINIT(7) WINIT(8) WINIT(9) WINIT(10)
#undef WINIT
  const float inv_ = 1.f / (wv0 + wv1 + wv2 + wv3 + wv4 + wv5 + wv6 + wv7 + wv8 + wv9 + wv10);
#define WNORM(k) wv##k = __int_as_float(__builtin_amdgcn_readfirstlane(__float_as_int(wv##k * inv_)));
  WNORM(0) WNORM(1) WNORM(2) WNORM(3) WNORM(4) WNORM(5)
  WNORM(6) WNORM(7) WNORM(8) WNORM(9) WNORM(10)
#undef WNORM

  // per-lane DMA sources: slot float f = 64*i + lane; pair p=f>>1 (col C0-8+p),
  // even floats source x, odd source y. Invalid lanes read zero page (stride 0).
  const float *pS0, *pS1, *pS2;
  unsigned st0, st1, st2;
#define MKSRC(i, PS, ST) { \
  const int fidx = 64 * (i) + lane; \
  const int p = fidx >> 1; \
  const int gcol = C0 - PADL + p; \
  const bool ok = (p < 80) && (gcol >= 0) && (gcol < WW); \
  PS = ok ? (((fidx & 1) ? yp : xp) + gcol) : zp; \
  ST = ok ? (unsigned)(WW * 4) : 0u; }
  MKSRC(0, pS0, st0)
  MKSRC(1, pS1, st1)
  MKSRC(2, pS2, st2)
#undef MKSRC

  // named ring: 11 slots x {a:v2f, b:v2f, c:float} = 55 VGPRs
  v2f a0,a1,a2,a3,a4,a5,a6,a7,a8,a9,a10;
  v2f b0,b1,b2,b3,b4,b5,b6,b7,b8,b9,b10;
  float c0,c1,c2,c3,c4,c5,c6,c7,c8,c9,c10;
  float acc = 0.f;

  // prologue: rows R0-5..R0+5 -> slots 0..10, rows R0+6,R0+7 -> slots 0,1
  for (int s = 0; s < NS; ++s)
    dma_rowpair(wptr + s * SLOT_FLOATS, R0 - HALO + s, pS0, st0, pS1, st1, pS2, st2, zp);
  dma_rowpair(wptr + 0 * SLOT_FLOATS, R0 + 6, pS0, st0, pS1, st1, pS2, st2, zp);
  dma_rowpair(wptr + 1 * SLOT_FLOATS, R0 + 7, pS0, st0, pS1, st1, pS2, st2, zp);
  asm volatile("s_waitcnt vmcnt(9)" ::: "memory");   // slots 0..9 landed

  // ring fill: h-blur raw rows R0-5..R0+4 (slots 0..9)
  HBLUR(0) HBLUR(1) HBLUR(2) HBLUR(3) HBLUR(4)
  HBLUR(5) HBLUR(6) HBLUR(7) HBLUR(8) HBLUR(9)

  // 64 live phases: 5 groups x 11 + 9 tail, uniform vmcnt schedule
  #pragma unroll 1
  for (int g = 0; g < 5; ++g) {
    const int qb = 11 * g;
    PHASE(qb + 0 , 10, 2,  0,1,2,3,4,5,6,7,8,9,10)
    PHASE(qb + 1 , 0 , 3,  1,2,3,4,5,6,7,8,9,10,0)
    PHASE(qb + 2 , 1 , 4,  2,3,4,5,6,7,8,9,10,0,1)
    PHASE(qb + 3 , 2 , 5,  3,4,5,6,7,8,9,10,0,1,2)
    PHASE(qb + 4 , 3 , 6,  4,5,6,7,8,9,10,0,1,2,3)
    PHASE(qb + 5 , 4 , 7,  5,6,7,8,9,10,0,1,2,3,4)
    PHASE(qb + 6 , 5 , 8,  6,7,8,9,10,0,1,2,3,4,5)
    PHASE(qb + 7 , 6 , 9,  7,8,9,10,0,1,2,3,4,5,6)
    PHASE(qb + 8 , 7 , 10, 8,9,10,0,1,2,3,4,5,6,7)
    PHASE(qb + 9 , 8 , 0,  9,10,0,1,2,3,4,5,6,7,8)
    PHASE(qb + 10, 9 , 1,  10,0,1,2,3,4,5,6,7,8,9)
  }
  PHASE(55, 10, 2,  0,1,2,3,4,5,6,7,8,9,10)
  PHASE(56, 0 , 3,  1,2,3,4,5,6,7,8,9,10,0)
  PHASE(57, 1 , 4,  2,3,4,5,6,7,8,9,10,0,1)
  PHASE(58, 2 , 5,  3,4,5,6,7,8,9,10,0,1,2)
  PHASE(59, 3 , 6,  4,5,6,7,8,9,10,0,1,2,3)
  PHASE(60, 4 , 7,  5,6,7,8,9,10,0,1,2,3,4)
  PHASE(61, 5 , 8,  6,7,8,9,10,0,1,2,3,4,5)
  PHASE(62, 6 , 9,  7,8,9,10,0,1,2,3,4,5,6)
  PHASE(63, 7 , 10, 8,9,10,0,1,2,3,4,5,6,7)

  // drain this wave's outstanding DMA before its LDS region is reused/freed
  asm volatile("s_waitcnt vmcnt(0)" ::: "memory");

  // per-wave shuffle reduction -> deterministic per-wave partial (no barriers)
  float a = acc;
  #pragma unroll
  for (int off = 32; off > 0; off >>= 1) a += __shfl_down(a, off);
  if (lane == 0)
    partial[(plane * 8 + wband) * 8 + colT] = a;
}

__global__ void zero_ws_kernel(float* __restrict__ ws)
{
  ws[threadIdx.x] = 0.f;   // zero page
}

__global__ void finalize_kernel(const float* __restrict__ partial, float* __restrict__ out)
{
  __shared__ float s4[4];
  float a = 0.f;
  for (int i = threadIdx.x; i < NPART; i += 256) a += partial[i];
  #pragma unroll
  for (int off = 32; off > 0; off >>= 1) a += __shfl_down(a, off);
  if ((threadIdx.x & 63) == 0) s4[threadIdx.x >> 6] = a;
  __syncthreads();
  if (threadIdx.x == 0) out[0] = 1.f - (s4[0] + s4[1] + s4[2] + s4[3]) * (1.f / NPIX);
}

extern "C" void kernel_launch(void* const* d_in, const int* in_sizes, int n_in,
                              void* d_out, int out_size, void* d_ws, size_t ws_size,
                              hipStream_t stream)
{
  const float* x = (const float*)d_in[0];
  const float* y = (const float*)d_in[1];
  float* ws = (float*)d_ws;
  float* out = (float*)d_out;

  hipLaunchKernelGGL(zero_ws_kernel, dim3(1), dim3(256), 0, stream, ws);
  hipLaunchKernelGGL(ssim_main, dim3(COL_TILES, ROW_GROUPS, NPLANES), dim3(BLOCK),
                     0, stream, x, y, ws);
  hipLaunchKernelGGL(finalize_kernel, dim3(1), dim3(256), 0, stream, ws + 256, out);
}

// Round 10
// 119.641 us; speedup vs baseline: 1.0588x; 1.0588x over previous
//
#include <hip/hip_runtime.h>

typedef float v2f __attribute__((ext_vector_type(2)));

#define HH 512
#define WW 512
#define NPLANES 96
#define BLOCK 64          // 1 wave per block -> no barriers anywhere
#define COLS_PB 64        // 1 column per thread
#define ROWS_PB 64
#define COL_TILES 8       // 512 / 64
#define ROW_TILES 8       // 512 / 64
#define HALO 5
#define NS 11             // LDS ring slots == named register ring depth
#define SLOT_V2 96        // v2f pairs per slot (192 floats; data pairs 0..79, junk 80..95)
#define PADL 8            // pair p <-> global col C0-8+p

#define C1V 1e-4f
#define C2V 9e-4f
#define EPSV 1e-8f
#define NPIX 25165824.0f  // 32*3*512*512
#define NBLK (COL_TILES * ROW_TILES * NPLANES)   // 6144

__device__ __forceinline__ void gld4(const float* g, float* l) {
  __builtin_amdgcn_global_load_lds((const __attribute__((address_space(1))) void*)g,
                                   (__attribute__((address_space(3))) void*)l, 4, 0, 0);
}

// stage one interleaved {x,y} row into a slot: 3 DMA instrs (4B/lane), rows
// out of [0,512) read the zero page (stride 0 folds col-invalid lanes too).
__device__ __forceinline__ void dma_rowpair(float* dst, int rw,
    const float* pS0, unsigned st0, const float* pS1, unsigned st1,
    const float* pS2, unsigned st2, const float* zp)
{
  const bool rok = (unsigned)rw < (unsigned)HH;
  const float* a0 = rok ? (const float*)((uintptr_t)pS0 + (unsigned)rw * st0) : zp;
  const float* a1 = rok ? (const float*)((uintptr_t)pS1 + (unsigned)rw * st1) : zp;
  const float* a2 = rok ? (const float*)((uintptr_t)pS2 + (unsigned)rw * st2) : zp;
  gld4(a0, dst);
  gld4(a1, dst + 64);
  gld4(a2, dst + 128);
}

// ---- forced VOP3P packed fp32 (CDNA4 full-rate): one instr = 2 fp32 ops ----
// dst/acc v2f in VGPR pair; weight pair in SGPR pair (1 sgpr read: legal).
#define PK_MUL_S(d, wp, b)  asm("v_pk_mul_f32 %0, %1, %2"     : "=v"(d)  : "s"(wp), "v"(b))
#define PK_FMA_S(acc, wp, b) asm("v_pk_fma_f32 %0, %1, %2, %0" : "+v"(acc): "s"(wp), "v"(b))
#define PK_ADD_V(acc, a)     asm("v_pk_add_f32 %0, %1, %0"     : "+v"(acc): "v"(a))
#define PK_FMA_V(acc, a, b)  asm("v_pk_fma_f32 %0, %1, %2, %0" : "+v"(acc): "v"(a), "v"(b))

// ---- all ring/weight/tap values are NAMED variables (no arrays anywhere) ----

// tap k: one aligned ds_read_b64 gives {x,y}; packed math:
//   wt = w*{x,y}; sa += wt; sb += wt*{x,y}; sc += wt.x*{y}
#define TAP(K) { \
  const v2f tk = pb_[K]; \
  v2f wt; PK_MUL_S(wt, wp##K, tk); \
  PK_ADD_V(sa, wt); \
  PK_FMA_V(sb, wt, tk); \
  sc = fmaf(wt.x, tk.y, sc); }

#define HBLUR(S) { \
  const v2f* pb_ = ldsv2 + (S) * SLOT_V2 + t + 3; \
  v2f sa = {0.f, 0.f}, sb = {0.f, 0.f}; float sc = 0.f; \
  TAP(0) TAP(1) TAP(2) TAP(3) TAP(4) TAP(5) \
  TAP(6) TAP(7) TAP(8) TAP(9) TAP(10) \
  a##S = sa; b##S = sb; c##S = sc; }

// vertical 11-tap blur over named ring slots + SSIM epilogue
#define VEPI(p0,p1,p2,p3,p4,p5,p6,p7,p8,p9,p10) { \
  v2f ma; PK_MUL_S(ma, wp0, a##p0); \
  PK_FMA_S(ma, wp1,  a##p1);  PK_FMA_S(ma, wp2,  a##p2); \
  PK_FMA_S(ma, wp3,  a##p3);  PK_FMA_S(ma, wp4,  a##p4); \
  PK_FMA_S(ma, wp5,  a##p5);  PK_FMA_S(ma, wp6,  a##p6); \
  PK_FMA_S(ma, wp7,  a##p7);  PK_FMA_S(ma, wp8,  a##p8); \
  PK_FMA_S(ma, wp9,  a##p9);  PK_FMA_S(ma, wp10, a##p10); \
  v2f mb; PK_MUL_S(mb, wp0, b##p0); \
  PK_FMA_S(mb, wp1,  b##p1);  PK_FMA_S(mb, wp2,  b##p2); \
  PK_FMA_S(mb, wp3,  b##p3);  PK_FMA_S(mb, wp4,  b##p4); \
  PK_FMA_S(mb, wp5,  b##p5);  PK_FMA_S(mb, wp6,  b##p6); \
  PK_FMA_S(mb, wp7,  b##p7);  PK_FMA_S(mb, wp8,  b##p8); \
  PK_FMA_S(mb, wp9,  b##p9);  PK_FMA_S(mb, wp10, b##p10); \
  float mc = wv0 * c##p0; \
  mc = fmaf(wv1,  c##p1,  mc); mc = fmaf(wv2,  c##p2,  mc); \
  mc = fmaf(wv3,  c##p3,  mc); mc = fmaf(wv4,  c##p4,  mc); \
  mc = fmaf(wv5,  c##p5,  mc); mc = fmaf(wv6,  c##p6,  mc); \
  mc = fmaf(wv7,  c##p7,  mc); mc = fmaf(wv8,  c##p8,  mc); \
  mc = fmaf(wv9,  c##p9,  mc); mc = fmaf(wv10, c##p10, mc); \
  const v2f mm = ma * ma;                 /* {mx2, my2} */ \
  const float mxy = ma.x * ma.y; \
  const v2f sv = mb - mm;                 /* {sx2, sy2} */ \
  const float sxy = mc - mxy; \
  const float num = fmaf(2.f, mxy, C1V) * fmaf(2.f, sxy, C2V); \
  const float den = (mm.x + mm.y + C1V) * (sv.x + sv.y + C2V) + EPSV; \
  acc = fmaf(num, __builtin_amdgcn_rcpf(den), acc); }

// phase q: DMA row R0+8+q (3 instrs; 3 rows = 9 instrs in flight) into retired
// slot (q+2)%11, counted vmcnt(9) -> row R0+5+q landed, h-blur it into ring
// slot (q+10)%11, vertical blur + epilogue for output row R0+q.
#define PHASE(QV, SNEW, SDMA, p0,p1,p2,p3,p4,p5,p6,p7,p8,p9,p10) { \
  dma_rowpair(ldsF + (SDMA) * (SLOT_V2 * 2), R0 + 8 + (QV), \
              pS0, st0, pS1, st1, pS2, st2, zp); \
  asm volatile("s_waitcnt vmcnt(9)" ::: "memory"); \
  HBLUR(SNEW) \
  VEPI(p0,p1,p2,p3,p4,p5,p6,p7,p8,p9,p10) }

__global__ __launch_bounds__(BLOCK)
void ssim_main(const float* __restrict__ x, const float* __restrict__ y,
               float* __restrict__ ws)
{
  __shared__ float ldsF[NS * SLOT_V2 * 2];   // 8.25 KB

  const int t = threadIdx.x;
  const int colT = blockIdx.x & (COL_TILES - 1);
  const int rowT = blockIdx.x >> 3;
  const int plane = blockIdx.y;
  const int C0 = colT * COLS_PB;
  const int R0 = rowT * ROWS_PB;

  const float* xp = x + (ptrdiff_t)plane * (HH * WW);
  const float* yp = y + (ptrdiff_t)plane * (HH * WW);
  const float* zp = ws;                 // 256-float zero page (zeroed each launch)
  float* partial = ws + 256;
  const v2f* ldsv2 = (const v2f*)ldsF;

  // Gaussian window (exact reference formula), named scalars -> SGPRs
  float wv0, wv1, wv2, wv3, wv4, wv5, wv6, wv7, wv8, wv9, wv10;
#define WINIT(k) wv##k = expf(-((float)((k - 5) * (k - 5))) / 4.5f);
  WINIT(0) WINIT(1) WINIT(2) WINIT(3) WINIT(4) WINIT(5)
  WINIT(6) WINIT(7) WINIT(8) WINIT(9) WINIT(10)
#undef WINIT
  const float inv_ = 1.f / (wv0 + wv1 + wv2 + wv3 + wv4 + wv5 + wv6 + wv7 + wv8 + wv9 + wv10);
#define WNORM(k) wv##k = __int_as_float(__builtin_amdgcn_readfirstlane(__float_as_int(wv##k * inv_)));
  WNORM(0) WNORM(1) WNORM(2) WNORM(3) WNORM(4) WNORM(5)
  WNORM(6) WNORM(7) WNORM(8) WNORM(9) WNORM(10)
#undef WNORM

  // weight broadcast pairs {w,w} -> SGPR pairs (uniform, "s" constraint)
  const v2f wp0 = {wv0, wv0}, wp1 = {wv1, wv1}, wp2 = {wv2, wv2};
  const v2f wp3 = {wv3, wv3}, wp4 = {wv4, wv4}, wp5 = {wv5, wv5};
  const v2f wp6 = {wv6, wv6}, wp7 = {wv7, wv7}, wp8 = {wv8, wv8};
  const v2f wp9 = {wv9, wv9}, wp10 = {wv10, wv10};

  // per-lane DMA sources: slot float f = 64*i + lane; pair p=f>>1 (col C0-8+p),
  // even floats source x, odd source y. Invalid lanes read zero page (stride 0).
  const float *pS0, *pS1, *pS2;
  unsigned st0, st1, st2;
#define MKSRC(i, PS, ST) { \
  const int fidx = 64 * (i) + t; \
  const int p = fidx >> 1; \
  const int gcol = C0 - PADL + p; \
  const bool ok = (p < 80) && (gcol >= 0) && (gcol < WW); \
  PS = ok ? (((fidx & 1) ? yp : xp) + gcol) : zp; \
  ST = ok ? (unsigned)(WW * 4) : 0u; }
  MKSRC(0, pS0, st0)
  MKSRC(1, pS1, st1)
  MKSRC(2, pS2, st2)
#undef MKSRC

  // named ring: 11 slots x {a:v2f, b:v2f, c:float} = 55 VGPRs
  v2f a0,a1,a2,a3,a4,a5,a6,a7,a8,a9,a10;
  v2f b0,b1,b2,b3,b4,b5,b6,b7,b8,b9,b10;
  float c0,c1,c2,c3,c4,c5,c6,c7,c8,c9,c10;
  float acc = 0.f;

  // prologue: rows R0-5..R0+5 -> slots 0..10, rows R0+6,R0+7 -> slots 0,1
  for (int s = 0; s < NS; ++s)
    dma_rowpair(ldsF + s * (SLOT_V2 * 2), R0 - HALO + s, pS0, st0, pS1, st1, pS2, st2, zp);
  dma_rowpair(ldsF + 0 * (SLOT_V2 * 2), R0 + 6, pS0, st0, pS1, st1, pS2, st2, zp);
  dma_rowpair(ldsF + 1 * (SLOT_V2 * 2), R0 + 7, pS0, st0, pS1, st1, pS2, st2, zp);
  asm volatile("s_waitcnt vmcnt(9)" ::: "memory");   // slots 0..9 landed

  // ring fill: h-blur raw rows R0-5..R0+4 (slots 0..9)
  HBLUR(0) HBLUR(1) HBLUR(2) HBLUR(3) HBLUR(4)
  HBLUR(5) HBLUR(6) HBLUR(7) HBLUR(8) HBLUR(9)

  // 64 live phases: 5 groups x 11 + 9 tail, uniform vmcnt schedule
  #pragma unroll 1
  for (int g = 0; g < 5; ++g) {
    const int qb = 11 * g;
    PHASE(qb + 0 , 10, 2,  0,1,2,3,4,5,6,7,8,9,10)
    PHASE(qb + 1 , 0 , 3,  1,2,3,4,5,6,7,8,9,10,0)
    PHASE(qb + 2 , 1 , 4,  2,3,4,5,6,7,8,9,10,0,1)
    PHASE(qb + 3 , 2 , 5,  3,4,5,6,7,8,9,10,0,1,2)
    PHASE(qb + 4 , 3 , 6,  4,5,6,7,8,9,10,0,1,2,3)
    PHASE(qb + 5 , 4 , 7,  5,6,7,8,9,10,0,1,2,3,4)
    PHASE(qb + 6 , 5 , 8,  6,7,8,9,10,0,1,2,3,4,5)
    PHASE(qb + 7 , 6 , 9,  7,8,9,10,0,1,2,3,4,5,6)
    PHASE(qb + 8 , 7 , 10, 8,9,10,0,1,2,3,4,5,6,7)
    PHASE(qb + 9 , 8 , 0,  9,10,0,1,2,3,4,5,6,7,8)
    PHASE(qb + 10, 9 , 1,  10,0,1,2,3,4,5,6,7,8,9)
  }
  PHASE(55, 10, 2,  0,1,2,3,4,5,6,7,8,9,10)
  PHASE(56, 0 , 3,  1,2,3,4,5,6,7,8,9,10,0)
  PHASE(57, 1 , 4,  2,3,4,5,6,7,8,9,10,0,1)
  PHASE(58, 2 , 5,  3,4,5,6,7,8,9,10,0,1,2)
  PHASE(59, 3 , 6,  4,5,6,7,8,9,10,0,1,2,3)
  PHASE(60, 4 , 7,  5,6,7,8,9,10,0,1,2,3,4)
  PHASE(61, 5 , 8,  6,7,8,9,10,0,1,2,3,4,5)
  PHASE(62, 6 , 9,  7,8,9,10,0,1,2,3,4,5,6)
  PHASE(63, 7 , 10, 8,9,10,0,1,2,3,4,5,6,7)

  // drain outstanding DMA before LDS goes away
  asm volatile("s_waitcnt vmcnt(0)" ::: "memory");

  // single-wave shuffle reduction -> deterministic per-block partial
  float a = acc;
  #pragma unroll
  for (int off = 32; off > 0; off >>= 1) a += __shfl_down(a, off);
  if (t == 0) partial[blockIdx.y * (COL_TILES * ROW_TILES) + blockIdx.x] = a;
}

__global__ void zero_ws_kernel(float* __restrict__ ws)
{
  ws[threadIdx.x] = 0.f;   // zero page
}

__global__ void finalize_kernel(const float* __restrict__ partial, float* __restrict__ out)
{
  __shared__ float s4[4];
  float a = 0.f;
  for (int i = threadIdx.x; i < NBLK; i += 256) a += partial[i];
  #pragma unroll
  for (int off = 32; off > 0; off >>= 1) a += __shfl_down(a, off);
  if ((threadIdx.x & 63) == 0) s4[threadIdx.x >> 6] = a;
  __syncthreads();
  if (threadIdx.x == 0) out[0] = 1.f - (s4[0] + s4[1] + s4[2] + s4[3]) * (1.f / NPIX);
}

extern "C" void kernel_launch(void* const* d_in, const int* in_sizes, int n_in,
                              void* d_out, int out_size, void* d_ws, size_t ws_size,
                              hipStream_t stream)
{
  const float* x = (const float*)d_in[0];
  const float* y = (const float*)d_in[1];
  float* ws = (float*)d_ws;
  float* out = (float*)d_out;

  hipLaunchKernelGGL(zero_ws_kernel, dim3(1), dim3(256), 0, stream, ws);
  hipLaunchKernelGGL(ssim_main, dim3(COL_TILES * ROW_TILES, NPLANES), dim3(BLOCK),
                     0, stream, x, y, ws);
  hipLaunchKernelGGL(finalize_kernel, dim3(1), dim3(256), 0, stream, ws + 256, out);
}

// Round 11
// 116.729 us; speedup vs baseline: 1.0853x; 1.0249x over previous
//
#include <hip/hip_runtime.h>

typedef float v2f __attribute__((ext_vector_type(2)));

#define HH 512
#define WW 512
#define NPLANES 96
#define BLOCK 64          // 1 wave per block -> no barriers anywhere
#define COLS_PB 64        // 1 column per thread
#define ROWS_PB 64
#define COL_TILES 8       // 512 / 64
#define ROW_TILES 8       // 512 / 64
#define HALO 5
#define NS 11             // LDS ring slots == named register ring depth
#define SLOT_V2 96        // v2f pairs per slot (192 floats; data pairs 0..79, junk 80..95)
#define PADL 8            // pair p <-> global col C0-8+p

#define C1V 1e-4f
#define C2V 9e-4f
#define EPSV 1e-8f
#define NPIX 25165824.0f  // 32*3*512*512
#define NBLK (COL_TILES * ROW_TILES * NPLANES)   // 6144

__device__ __forceinline__ void gld4(const float* g, float* l) {
  __builtin_amdgcn_global_load_lds((const __attribute__((address_space(1))) void*)g,
                                   (__attribute__((address_space(3))) void*)l, 4, 0, 0);
}

// stage one interleaved {x,y} row into a slot: 3 DMA instrs (4B/lane), rows
// out of [0,512) read the zero page (stride 0 folds col-invalid lanes too).
__device__ __forceinline__ void dma_rowpair(float* dst, int rw,
    const float* pS0, unsigned st0, const float* pS1, unsigned st1,
    const float* pS2, unsigned st2, const float* zp)
{
  const bool rok = (unsigned)rw < (unsigned)HH;
  const float* a0 = rok ? (const float*)((uintptr_t)pS0 + (unsigned)rw * st0) : zp;
  const float* a1 = rok ? (const float*)((uintptr_t)pS1 + (unsigned)rw * st1) : zp;
  const float* a2 = rok ? (const float*)((uintptr_t)pS2 + (unsigned)rw * st2) : zp;
  gld4(a0, dst);
  gld4(a1, dst + 64);
  gld4(a2, dst + 128);
}

// ---- VOP3P packed fp32 (half-rate on CDNA4 = scalar-equivalent cycles, but
// half the instruction slots -> leaves issue room for DS/DMA) ----
#define PK_MUL_S(d, wp, b)   asm("v_pk_mul_f32 %0, %1, %2"     : "=v"(d)  : "s"(wp), "v"(b))
#define PK_FMA_S(acc, wp, b) asm("v_pk_fma_f32 %0, %1, %2, %0" : "+v"(acc): "s"(wp), "v"(b))
#define PK_ADD_V(acc, a)     asm("v_pk_add_f32 %0, %1, %0"     : "+v"(acc): "v"(a))
#define PK_FMA_V(acc, a, b)  asm("v_pk_fma_f32 %0, %1, %2, %0" : "+v"(acc): "v"(a), "v"(b))

// ---- all ring/weight/tap values are NAMED variables (no arrays anywhere) ----

// load next phase's 11 taps LDS -> named registers (prefetch; consumed next phase)
#define LOADT(S) { \
  const v2f* pb_ = ldsv2 + (S) * SLOT_V2 + t + 3; \
  T0 = pb_[0]; T1 = pb_[1]; T2 = pb_[2]; T3 = pb_[3]; T4 = pb_[4]; T5 = pb_[5]; \
  T6 = pb_[6]; T7 = pb_[7]; T8 = pb_[8]; T9 = pb_[9]; T10 = pb_[10]; }

// h-blur from the prefetched tap registers -> ring slot S
#define TAPT(K) { \
  v2f wt; PK_MUL_S(wt, wp##K, T##K); \
  PK_ADD_V(sa, wt); \
  PK_FMA_V(sb, wt, T##K); \
  sc = fmaf(wt.x, T##K.y, sc); }

#define HBLUR_T(S) { \
  v2f sa = {0.f, 0.f}, sb = {0.f, 0.f}; float sc = 0.f; \
  TAPT(0) TAPT(1) TAPT(2) TAPT(3) TAPT(4) TAPT(5) \
  TAPT(6) TAPT(7) TAPT(8) TAPT(9) TAPT(10) \
  a##S = sa; b##S = sb; c##S = sc; }

// prologue-only: h-blur reading LDS directly (latency exposed once)
#define TAPL(K) { \
  const v2f tk = pb_[K]; \
  v2f wt; PK_MUL_S(wt, wp##K, tk); \
  PK_ADD_V(sa, wt); \
  PK_FMA_V(sb, wt, tk); \
  sc = fmaf(wt.x, tk.y, sc); }

#define HBLUR_LDS(S) { \
  const v2f* pb_ = ldsv2 + (S) * SLOT_V2 + t + 3; \
  v2f sa = {0.f, 0.f}, sb = {0.f, 0.f}; float sc = 0.f; \
  TAPL(0) TAPL(1) TAPL(2) TAPL(3) TAPL(4) TAPL(5) \
  TAPL(6) TAPL(7) TAPL(8) TAPL(9) TAPL(10) \
  a##S = sa; b##S = sb; c##S = sc; }

// vertical 11-tap blur over named ring slots + SSIM epilogue
#define VEPI(p0,p1,p2,p3,p4,p5,p6,p7,p8,p9,p10) { \
  v2f ma; PK_MUL_S(ma, wp0, a##p0); \
  PK_FMA_S(ma, wp1,  a##p1);  PK_FMA_S(ma, wp2,  a##p2); \
  PK_FMA_S(ma, wp3,  a##p3);  PK_FMA_S(ma, wp4,  a##p4); \
  PK_FMA_S(ma, wp5,  a##p5);  PK_FMA_S(ma, wp6,  a##p6); \
  PK_FMA_S(ma, wp7,  a##p7);  PK_FMA_S(ma, wp8,  a##p8); \
  PK_FMA_S(ma, wp9,  a##p9);  PK_FMA_S(ma, wp10, a##p10); \
  v2f mb; PK_MUL_S(mb, wp0, b##p0); \
  PK_FMA_S(mb, wp1,  b##p1);  PK_FMA_S(mb, wp2,  b##p2); \
  PK_FMA_S(mb, wp3,  b##p3);  PK_FMA_S(mb, wp4,  b##p4); \
  PK_FMA_S(mb, wp5,  b##p5);  PK_FMA_S(mb, wp6,  b##p6); \
  PK_FMA_S(mb, wp7,  b##p7);  PK_FMA_S(mb, wp8,  b##p8); \
  PK_FMA_S(mb, wp9,  b##p9);  PK_FMA_S(mb, wp10, b##p10); \
  float mc = wv0 * c##p0; \
  mc = fmaf(wv1,  c##p1,  mc); mc = fmaf(wv2,  c##p2,  mc); \
  mc = fmaf(wv3,  c##p3,  mc); mc = fmaf(wv4,  c##p4,  mc); \
  mc = fmaf(wv5,  c##p5,  mc); mc = fmaf(wv6,  c##p6,  mc); \
  mc = fmaf(wv7,  c##p7,  mc); mc = fmaf(wv8,  c##p8,  mc); \
  mc = fmaf(wv9,  c##p9,  mc); mc = fmaf(wv10, c##p10, mc); \
  const v2f mm = ma * ma;                 /* {mx2, my2} */ \
  const float mxy = ma.x * ma.y; \
  const v2f sv = mb - mm;                 /* {sx2, sy2} */ \
  const float sxy = mc - mxy; \
  const float num = fmaf(2.f, mxy, C1V) * fmaf(2.f, sxy, C2V); \
  const float den = (mm.x + mm.y + C1V) * (sv.x + sv.y + C2V) + EPSV; \
  acc = fmaf(num, __builtin_amdgcn_rcpf(den), acc); }

// phase q: consume prefetched taps (row R0+5+q, slot SNEW=(q+10)%11) into the
// ring; issue DMA row R0+8+q into retired slot SDMA=(q+2)%11; vmcnt(6) ->
// slot SRD=q%11 (row R0+6+q, issued 2 phases ago) landed; prefetch its taps
// into T; VEPI (its ~110 VALU cycles cover the ds_read latency).
#define PHASE(QV, SNEW, SDMA, SRD, p0,p1,p2,p3,p4,p5,p6,p7,p8,p9,p10) { \
  HBLUR_T(SNEW) \
  dma_rowpair(ldsF + (SDMA) * (SLOT_V2 * 2), R0 + 8 + (QV), \
              pS0, st0, pS1, st1, pS2, st2, zp); \
  asm volatile("s_waitcnt vmcnt(6)" ::: "memory"); \
  LOADT(SRD) \
  VEPI(p0,p1,p2,p3,p4,p5,p6,p7,p8,p9,p10) }

__global__ __launch_bounds__(BLOCK)
void ssim_main(const float* __restrict__ x, const float* __restrict__ y,
               float* __restrict__ ws)
{
  __shared__ float ldsF[NS * SLOT_V2 * 2];   // 8.25 KB

  const int t = threadIdx.x;
  const int colT = blockIdx.x & (COL_TILES - 1);
  const int rowT = blockIdx.x >> 3;
  const int plane = blockIdx.y;
  const int C0 = colT * COLS_PB;
  const int R0 = rowT * ROWS_PB;

  const float* xp = x + (ptrdiff_t)plane * (HH * WW);
  const float* yp = y + (ptrdiff_t)plane * (HH * WW);
  const float* zp = ws;                 // 256-float zero page (zeroed each launch)
  float* partial = ws + 256;
  const v2f* ldsv2 = (const v2f*)ldsF;

  // Gaussian window (exact reference formula), named scalars -> SGPRs
  float wv0, wv1, wv2, wv3, wv4, wv5, wv6, wv7, wv8, wv9, wv10;
#define WINIT(k) wv##k = expf(-((float)((k - 5) * (k - 5))) / 4.5f);
  WINIT(0) WINIT(1) WINIT(2) WINIT(3) WINIT(4) WINIT(5)
  WINIT(6) WINIT(7) WINIT(8) WINIT(9) WINIT(10)
#undef WINIT
  const float inv_ = 1.f / (wv0 + wv1 + wv2 + wv3 + wv4 + wv5 + wv6 + wv7 + wv8 + wv9 + wv10);
#define WNORM(k) wv##k = __int_as_float(__builtin_amdgcn_readfirstlane(__float_as_int(wv##k * inv_)));
  WNORM(0) WNORM(1) WNORM(2) WNORM(3) WNORM(4) WNORM(5)
  WNORM(6) WNORM(7) WNORM(8) WNORM(9) WNORM(10)
#undef WNORM

  // weight broadcast pairs {w,w} -> SGPR pairs (uniform, "s" constraint)
  const v2f wp0 = {wv0, wv0}, wp1 = {wv1, wv1}, wp2 = {wv2, wv2};
  const v2f wp3 = {wv3, wv3}, wp4 = {wv4, wv4}, wp5 = {wv5, wv5};
  const v2f wp6 = {wv6, wv6}, wp7 = {wv7, wv7}, wp8 = {wv8, wv8};
  const v2f wp9 = {wv9, wv9}, wp10 = {wv10, wv10};

  // per-lane DMA sources: slot float f = 64*i + lane; pair p=f>>1 (col C0-8+p),
  // even floats source x, odd source y. Invalid lanes read zero page (stride 0).
  const float *pS0, *pS1, *pS2;
  unsigned st0, st1, st2;
#define MKSRC(i, PS, ST) { \
  const int fidx = 64 * (i) + t; \
  const int p = fidx >> 1; \
  const int gcol = C0 - PADL + p; \
  const bool ok = (p < 80) && (gcol >= 0) && (gcol < WW); \
  PS = ok ? (((fidx & 1) ? yp : xp) + gcol) : zp; \
  ST = ok ? (unsigned)(WW * 4) : 0u; }
  MKSRC(0, pS0, st0)
  MKSRC(1, pS1, st1)
  MKSRC(2, pS2, st2)
#undef MKSRC

  // named ring: 11 slots x {a:v2f, b:v2f, c:float} = 55 VGPRs
  v2f a0,a1,a2,a3,a4,a5,a6,a7,a8,a9,a10;
  v2f b0,b1,b2,b3,b4,b5,b6,b7,b8,b9,b10;
  float c0,c1,c2,c3,c4,c5,c6,c7,c8,c9,c10;
  // prefetched tap registers (22 VGPRs)
  v2f T0,T1,T2,T3,T4,T5,T6,T7,T8,T9,T10;
  float acc = 0.f;

  // prologue: rows R0-5..R0+5 -> slots 0..10, rows R0+6,R0+7 -> slots 0,1
  for (int s = 0; s < NS; ++s)
    dma_rowpair(ldsF + s * (SLOT_V2 * 2), R0 - HALO + s, pS0, st0, pS1, st1, pS2, st2, zp);
  dma_rowpair(ldsF + 0 * (SLOT_V2 * 2), R0 + 6, pS0, st0, pS1, st1, pS2, st2, zp);
  dma_rowpair(ldsF + 1 * (SLOT_V2 * 2), R0 + 7, pS0, st0, pS1, st1, pS2, st2, zp);
  asm volatile("s_waitcnt vmcnt(6)" ::: "memory");   // slots 0..10 landed

  // ring fill: h-blur raw rows R0-5..R0+4 (slots 0..9), then prefetch slot 10
  HBLUR_LDS(0) HBLUR_LDS(1) HBLUR_LDS(2) HBLUR_LDS(3) HBLUR_LDS(4)
  HBLUR_LDS(5) HBLUR_LDS(6) HBLUR_LDS(7) HBLUR_LDS(8) HBLUR_LDS(9)
  LOADT(10)   // taps of row R0+5 for phase 0

  // 64 live phases: 5 groups x 11 + 9 tail, uniform vmcnt schedule
  #pragma unroll 1
  for (int g = 0; g < 5; ++g) {
    const int qb = 11 * g;
    PHASE(qb + 0 , 10, 2 , 0 ,  0,1,2,3,4,5,6,7,8,9,10)
    PHASE(qb + 1 , 0 , 3 , 1 ,  1,2,3,4,5,6,7,8,9,10,0)
    PHASE(qb + 2 , 1 , 4 , 2 ,  2,3,4,5,6,7,8,9,10,0,1)
    PHASE(qb + 3 , 2 , 5 , 3 ,  3,4,5,6,7,8,9,10,0,1,2)
    PHASE(qb + 4 , 3 , 6 , 4 ,  4,5,6,7,8,9,10,0,1,2,3)
    PHASE(qb + 5 , 4 , 7 , 5 ,  5,6,7,8,9,10,0,1,2,3,4)
    PHASE(qb + 6 , 5 , 8 , 6 ,  6,7,8,9,10,0,1,2,3,4,5)
    PHASE(qb + 7 , 6 , 9 , 7 ,  7,8,9,10,0,1,2,3,4,5,6)
    PHASE(qb + 8 , 7 , 10, 8 ,  8,9,10,0,1,2,3,4,5,6,7)
    PHASE(qb + 9 , 8 , 0 , 9 ,  9,10,0,1,2,3,4,5,6,7,8)
    PHASE(qb + 10, 9 , 1 , 10,  10,0,1,2,3,4,5,6,7,8,9)
  }
  PHASE(55, 10, 2 , 0 ,  0,1,2,3,4,5,6,7,8,9,10)
  PHASE(56, 0 , 3 , 1 ,  1,2,3,4,5,6,7,8,9,10,0)
  PHASE(57, 1 , 4 , 2 ,  2,3,4,5,6,7,8,9,10,0,1)
  PHASE(58, 2 , 5 , 3 ,  3,4,5,6,7,8,9,10,0,1,2)
  PHASE(59, 3 , 6 , 4 ,  4,5,6,7,8,9,10,0,1,2,3)
  PHASE(60, 4 , 7 , 5 ,  5,6,7,8,9,10,0,1,2,3,4)
  PHASE(61, 5 , 8 , 6 ,  6,7,8,9,10,0,1,2,3,4,5)
  PHASE(62, 6 , 9 , 7 ,  7,8,9,10,0,1,2,3,4,5,6)
  PHASE(63, 7 , 10, 8 ,  8,9,10,0,1,2,3,4,5,6,7)

  // drain outstanding DMA before LDS goes away
  asm volatile("s_waitcnt vmcnt(0)" ::: "memory");

  // single-wave shuffle reduction -> deterministic per-block partial
  float a = acc;
  #pragma unroll
  for (int off = 32; off > 0; off >>= 1) a += __shfl_down(a, off);
  if (t == 0) partial[blockIdx.y * (COL_TILES * ROW_TILES) + blockIdx.x] = a;
}

__global__ void zero_ws_kernel(float* __restrict__ ws)
{
  ws[threadIdx.x] = 0.f;   // zero page
}

__global__ void finalize_kernel(const float* __restrict__ partial, float* __restrict__ out)
{
  __shared__ float s4[4];
  float a = 0.f;
  for (int i = threadIdx.x; i < NBLK; i += 256) a += partial[i];
  #pragma unroll
  for (int off = 32; off > 0; off >>= 1) a += __shfl_down(a, off);
  if ((threadIdx.x & 63) == 0) s4[threadIdx.x >> 6] = a;
  __syncthreads();
  if (threadIdx.x == 0) out[0] = 1.f - (s4[0] + s4[1] + s4[2] + s4[3]) * (1.f / NPIX);
}

extern "C" void kernel_launch(void* const* d_in, const int* in_sizes, int n_in,
                              void* d_out, int out_size, void* d_ws, size_t ws_size,
                              hipStream_t stream)
{
  const float* x = (const float*)d_in[0];
  const float* y = (const float*)d_in[1];
  float* ws = (float*)d_ws;
  float* out = (float*)d_out;

  hipLaunchKernelGGL(zero_ws_kernel, dim3(1), dim3(256), 0, stream, ws);
  hipLaunchKernelGGL(ssim_main, dim3(COL_TILES * ROW_TILES, NPLANES), dim3(BLOCK),
                     0, stream, x, y, ws);
  hipLaunchKernelGGL(finalize_kernel, dim3(1), dim3(256), 0, stream, ws + 256, out);
}

// Round 13
// 65.799 us; speedup vs baseline: 1.9253x; 1.7740x over previous
//
#include <hip/hip_runtime.h>

typedef float v4f   __attribute__((ext_vector_type(4)));
typedef float f32x4 __attribute__((ext_vector_type(4)));
typedef _Float16 h4 __attribute__((ext_vector_type(4)));
typedef _Float16 h8 __attribute__((ext_vector_type(8)));

#define HH 512
#define WW 512
#define NPLANES 96
#define NSTRIP 32
#define NBLK (NPLANES * NSTRIP)   // 3072
#define C1V 1e-4f
#define C2V 9e-4f
#define EPSV 1e-8f
#define NPIX 25165824.0f          // 32*3*512*512

// LDS H-ring: [q 5][slot 5][col 16][48 B]; slots 0..3 ring, slot 4 = zeros.
// 48B col stride: 32B data (16 rows f16) + 16B pad; 48 % 16 == 0 -> b128-aligned.
#define SLOT_B 768                // 16 cols * 48 B
#define Q_B    3840               // 5 slots
#define LDS_B  19200

#define MF(A, B) __builtin_amdgcn_mfma_f32_16x16x32_f16((A), (B), zf, 0, 0, 0)

// 11-way select from named weight scalars (no arrays -> no scratch)
#define SELW(DST, IX) { const int ix_ = (IX); float r_ = 0.f; \
  r_ = (ix_ == 0) ? wv0 : r_;  r_ = (ix_ == 1) ? wv1 : r_; \
  r_ = (ix_ == 2) ? wv2 : r_;  r_ = (ix_ == 3) ? wv3 : r_; \
  r_ = (ix_ == 4) ? wv4 : r_;  r_ = (ix_ == 5) ? wv5 : r_; \
  r_ = (ix_ == 6) ? wv6 : r_;  r_ = (ix_ == 7) ? wv7 : r_; \
  r_ = (ix_ == 8) ? wv8 : r_;  r_ = (ix_ == 9) ? wv9 : r_; \
  r_ = (ix_ == 10) ? wv10 : r_; DST = r_; }

// f32 -> f16 pack via RNE casts (v_cvt_f16_f32), unbiased
#define PACK8(DST, F0,F1,F2,F3,F4,F5,F6,F7) \
  DST = (h8){(_Float16)(F0),(_Float16)(F1),(_Float16)(F2),(_Float16)(F3), \
             (_Float16)(F4),(_Float16)(F5),(_Float16)(F6),(_Float16)(F7)};

#define EPX(M) { \
  const float mux_ = mx[M], muy_ = my[M]; \
  const float mx2_ = mux_ * mux_, my2_ = muy_ * muy_, mxy_ = mux_ * muy_; \
  const float sx2_ = vx2[M] - mx2_, sy2_ = vy2[M] - my2_, sxy_ = vxy[M] - mxy_; \
  const float num_ = fmaf(2.f, mxy_, C1V) * fmaf(2.f, sxy_, C2V); \
  const float den_ = (mx2_ + my2_ + C1V) * (sx2_ + sy2_ + C2V) + EPSV; \
  acc = fmaf(num_, __builtin_amdgcn_rcpf(den_), acc); }

// V for out-chunk TAU: K window = H rows [16*TAU-8, 16*TAU+24); lane (n,s)
// needs 8 rows of col n from H chunk ch_ (zero slot if outside the image).
#define VSTEP(TAU) { \
  const int tau_ = (TAU); \
  const int ch_ = tau_ - 1 + ((s + 1) >> 1); \
  const int slot_ = ((unsigned)ch_ < 32u) ? (ch_ & 3) : 4; \
  const char* rb_ = lds + slot_ * SLOT_B + rByte; \
  const h8 bx  = *(const h8*)(rb_); \
  const h8 by  = *(const h8*)(rb_ + Q_B); \
  const h8 bx2 = *(const h8*)(rb_ + 2 * Q_B); \
  const h8 by2 = *(const h8*)(rb_ + 3 * Q_B); \
  const h8 bxy = *(const h8*)(rb_ + 4 * Q_B); \
  const f32x4 mx  = MF(Wf, bx);  const f32x4 my  = MF(Wf, by); \
  const f32x4 vx2 = MF(Wf, bx2); const f32x4 vy2 = MF(Wf, by2); \
  const f32x4 vxy = MF(Wf, bxy); \
  EPX(0) EPX(1) EPX(2) EPX(3) }

// one H chunk T (+ V of chunk T-1). CUR regs hold chunk T's raw taps;
// prefetch chunk T+1 into NXT (skipped at T=31).
#define STEP(T, CXA,CXB,CYA,CYB, NXA,NXB,NYA,NYB) { \
  const int t_ = (T); \
  if (t_ < 31) { \
    NXA = *(const v4f*)pXa; NXB = *(const v4f*)pXb; \
    NYA = *(const v4f*)pYa; NYB = *(const v4f*)pYb; \
    pXa += 16 * WW; pXb += 16 * WW; pYa += 16 * WW; pYb += 16 * WW; \
  } \
  h8 ax, ay; \
  PACK8(ax, CXA[0],CXA[1],CXA[2],CXA[3], CXB[0],CXB[1],CXB[2],CXB[3]) \
  PACK8(ay, CYA[0],CYA[1],CYA[2],CYA[3], CYB[0],CYB[1],CYB[2],CYB[3]) \
  const h8 ax2 = ax * ax, ay2 = ay * ay, axy = ax * ay; \
  const f32x4 chx  = MF(ax,  WfH); const f32x4 chy  = MF(ay,  WfH); \
  const f32x4 chx2 = MF(ax2, WfH); const f32x4 chy2 = MF(ay2, WfH); \
  const f32x4 chxy = MF(axy, WfH); \
  { char* wb_ = lds + (t_ & 3) * SLOT_B + wByte; \
    *(h4*)(wb_)         = (h4){(_Float16)chx[0], (_Float16)chx[1], (_Float16)chx[2], (_Float16)chx[3]}; \
    *(h4*)(wb_ + Q_B)   = (h4){(_Float16)chy[0], (_Float16)chy[1], (_Float16)chy[2], (_Float16)chy[3]}; \
    *(h4*)(wb_ + 2*Q_B) = (h4){(_Float16)chx2[0],(_Float16)chx2[1],(_Float16)chx2[2],(_Float16)chx2[3]}; \
    *(h4*)(wb_ + 3*Q_B) = (h4){(_Float16)chy2[0],(_Float16)chy2[1],(_Float16)chy2[2],(_Float16)chy2[3]}; \
    *(h4*)(wb_ + 4*Q_B) = (h4){(_Float16)chxy[0],(_Float16)chxy[1],(_Float16)chxy[2],(_Float16)chxy[3]}; } \
  if (t_ >= 1) VSTEP(t_ - 1) }

__global__ __launch_bounds__(64)
void ssim_main(const float* __restrict__ x, const float* __restrict__ y,
               float* __restrict__ partial)
{
  __shared__ __attribute__((aligned(16))) char lds[LDS_B];

  const int l = threadIdx.x;
  const int n = l & 15;     // H: A-row (image row in chunk); V: B/D col (out col)
  const int s = l >> 4;     // k quadrant (8 consecutive k)

  // XCD swizzle: each XCD gets 384 consecutive (plane,strip) units -> halo L2 reuse
  const int wg = blockIdx.x;
  const int swz = (wg & 7) * (NBLK / 8) + (wg >> 3);
  const int plane = swz >> 5;
  const int strip = swz & 31;
  const int C0 = strip * 16;

  const float* xp = x + (size_t)plane * (HH * WW);
  const float* yp = y + (size_t)plane * (HH * WW);

  // Gaussian window (exact reference formula), named scalars -> SGPRs
  float wv0, wv1, wv2, wv3, wv4, wv5, wv6, wv7, wv8, wv9, wv10;
#define WINIT(k) wv##k = expf(-((float)((k - 5) * (k - 5))) / 4.5f);
  WINIT(0) WINIT(1) WINIT(2) WINIT(3) WINIT(4) WINIT(5)
  WINIT(6) WINIT(7) WINIT(8) WINIT(9) WINIT(10)
#undef WINIT
  const float inv_ = 1.f / (wv0 + wv1 + wv2 + wv3 + wv4 + wv5 + wv6 + wv7 + wv8 + wv9 + wv10);
#define WNORM(k) wv##k = __int_as_float(__builtin_amdgcn_readfirstlane(__float_as_int(wv##k * inv_)));
  WNORM(0) WNORM(1) WNORM(2) WNORM(3) WNORM(4) WNORM(5)
  WNORM(6) WNORM(7) WNORM(8) WNORM(9) WNORM(10)
#undef WNORM

  const f32x4 zf = {0.f, 0.f, 0.f, 0.f};

  // shared banded weight fragment: W[k][i] = w[k-i-3], i = l&15, k = 8s+j.
  // Used as B in H (i=out-col) and as A in V (i=out-row) -- same registers.
  h8 Wf;
  {
    const int kb = 8 * s;
    float b0,b1,b2,b3,b4,b5,b6,b7;
    SELW(b0, kb + 0 - n - 3) SELW(b1, kb + 1 - n - 3)
    SELW(b2, kb + 2 - n - 3) SELW(b3, kb + 3 - n - 3)
    SELW(b4, kb + 4 - n - 3) SELW(b5, kb + 5 - n - 3)
    SELW(b6, kb + 6 - n - 3) SELW(b7, kb + 7 - n - 3)
    PACK8(Wf, b0,b1,b2,b3,b4,b5,b6,b7)
  }

  // H raw-tap window: cols C0-8+8s .. +7. Kill whole group if fully outside
  // (strip 0/s=0, strip 31/s=3): zero H weights; loads read clamped valid mem.
  const int cb = C0 - 8 + 8 * s;
  const bool kill = (cb < 0) || (cb >= WW);
  h8 WfH = Wf;
  if (kill) WfH = (h8)(_Float16)0.f;
  const int ca = kill ? 0 : cb;

  const float* pXa = xp + n * WW + ca;
  const float* pXb = pXa + 4;
  const float* pYa = yp + n * WW + ca;
  const float* pYb = pYa + 4;

  const int wByte = n * 48 + 8 * s;                    // store: col n, rows 4s..4s+3
  const int rByte = n * 48 + 16 * ((s + 1) & 1);       // read: col n, rowbase {8,0,8,0}

  // zero-slot init (slot 4, all 5 quantities)
  #pragma unroll
  for (int q = 0; q < 5; ++q)
    #pragma unroll
    for (int j = 0; j < 3; ++j)
      *(unsigned*)(lds + q * Q_B + 4 * SLOT_B + 4 * (l + 64 * j)) = 0u;

  float acc = 0.f;

  // prologue: chunk 0 into A-set
  v4f XA0 = *(const v4f*)pXa, XB0 = *(const v4f*)pXb;
  v4f YA0 = *(const v4f*)pYa, YB0 = *(const v4f*)pYb;
  pXa += 16 * WW; pXb += 16 * WW; pYa += 16 * WW; pYb += 16 * WW;
  v4f XA1, XB1, YA1, YB1;

  #pragma unroll 1
  for (int u = 0; u < 16; ++u) {
    STEP(2 * u,     XA0, XB0, YA0, YB0,  XA1, XB1, YA1, YB1)
    STEP(2 * u + 1, XA1, XB1, YA1, YB1,  XA0, XB0, YA0, YB0)
  }
  VSTEP(31)   // tail: last out-chunk (H chunks 30,31,zero)

  // wave reduction -> per-block partial
  #pragma unroll
  for (int off = 32; off > 0; off >>= 1) acc += __shfl_down(acc, off);
  if (l == 0) partial[wg] = acc;
}

__global__ void finalize_kernel(const float* __restrict__ partial, float* __restrict__ out)
{
  __shared__ float s4[4];
  float a = 0.f;
  for (int i = threadIdx.x; i < NBLK; i += 256) a += partial[i];
  #pragma unroll
  for (int off = 32; off > 0; off >>= 1) a += __shfl_down(a, off);
  if ((threadIdx.x & 63) == 0) s4[threadIdx.x >> 6] = a;
  __syncthreads();
  if (threadIdx.x == 0) out[0] = 1.f - (s4[0] + s4[1] + s4[2] + s4[3]) * (1.f / NPIX);
}

extern "C" void kernel_launch(void* const* d_in, const int* in_sizes, int n_in,
                              void* d_out, int out_size, void* d_ws, size_t ws_size,
                              hipStream_t stream)
{
  const float* x = (const float*)d_in[0];
  const float* y = (const float*)d_in[1];
  float* ws = (float*)d_ws;
  float* out = (float*)d_out;

  hipLaunchKernelGGL(ssim_main, dim3(NBLK), dim3(64), 0, stream, x, y, ws);
  hipLaunchKernelGGL(finalize_kernel, dim3(1), dim3(256), 0, stream, ws, out);
}